// Round 3
// baseline (379.267 us; speedup 1.0000x reference)
//
#include <hip/hip_runtime.h>

// BackWarp: dense bilinear backward warp with LDS tile staging.
// image: [B,H,W,C] f32, flow: [B,H,W,2] f32, out: [B,H,W,C] f32
// query = (y,x) - flow; bilinear with boundary clamp:
//   fy = clip(floor(qy), 0, H-2); ay = clip(qy - fy, 0, 1)   (same for x)
//
// flow ~ N(0,1) -> displacements within +/-5 px essentially always.
// Each block stages a (TILE_H+2*HALO+1) x (TILE_W+2*HALO+1) image tile into
// LDS (float4-padded pixels -> aligned ds_read_b128 gathers), with source
// coords clamped at image edges (duplicates never looked up in-range).
// Rare out-of-halo lanes (P ~ 5.7e-7) take a global-gather fallback.

#define BW_B 16
#define BW_H 720
#define BW_W 1280
#define BW_C 3

#define TILE_W 64
#define TILE_H 8
#define HALO 5
#define S_COLS (TILE_W + 2 * HALO + 1)  // 75
#define S_ROWS (TILE_H + 2 * HALO + 1)  // 19
#define S_PIX (S_ROWS * S_COLS)         // 1425 pixels, 22800 B as float4

__device__ __forceinline__ void lerp_store(
    float tl0, float tl1, float tl2, float tr0, float tr1, float tr2,
    float bl0, float bl1, float bl2, float br0, float br1, float br2,
    float ax, float ay, float* __restrict__ o) {
    const float it0 = tl0 + ax * (tr0 - tl0);
    const float it1 = tl1 + ax * (tr1 - tl1);
    const float it2 = tl2 + ax * (tr2 - tl2);
    const float ib0 = bl0 + ax * (br0 - bl0);
    const float ib1 = bl1 + ax * (br1 - bl1);
    const float ib2 = bl2 + ax * (br2 - bl2);
    __builtin_nontemporal_store(it0 + ay * (ib0 - it0), o + 0);
    __builtin_nontemporal_store(it1 + ay * (ib1 - it1), o + 1);
    __builtin_nontemporal_store(it2 + ay * (ib2 - it2), o + 2);
}

__global__ __launch_bounds__(256) void backwarp_kernel(
    const float* __restrict__ image,
    const float* __restrict__ flow,
    float* __restrict__ out) {
    __shared__ float4 tile[S_PIX];

    const int tid = threadIdx.y * TILE_W + threadIdx.x;  // block = (64,4)
    const int x0 = blockIdx.x * TILE_W;
    const int y0 = blockIdx.y * TILE_H;
    const int b = blockIdx.z;

    const int x = x0 + threadIdx.x;
    const int yA = y0 + threadIdx.y;  // rows ty and ty+4 of the 64x8 tile
    const int yB = yA + 4;

    const size_t base_b = (size_t)b * BW_H * BW_W;
    const size_t iA = base_b + (size_t)yA * BW_W + x;
    const size_t iB = base_b + (size_t)yB * BW_W + x;

    // issue flow loads early (overlap with staging)
    const float2 fA = reinterpret_cast<const float2*>(flow)[iA];
    const float2 fB = reinterpret_cast<const float2*>(flow)[iB];

    const int ry0 = y0 - HALO;  // staged global row of LDS row 0 (may be <0)
    const int rx0 = x0 - HALO;
    const float* __restrict__ imgb = image + base_b * BW_C;

    // ---- stage tile: coalesced global reads -> float4 LDS pixels ----
    for (int i = tid; i < S_PIX; i += 256) {
        const int r = i / S_COLS;
        const int c = i - r * S_COLS;
        const int gr = min(max(ry0 + r, 0), BW_H - 1);
        const int gc = min(max(rx0 + c, 0), BW_W - 1);
        const float* __restrict__ g = imgb + ((size_t)gr * BW_W + gc) * BW_C;
        tile[i] = make_float4(g[0], g[1], g[2], 0.0f);
    }
    __syncthreads();

    // ---- two pixels per thread ----
#pragma unroll
    for (int px = 0; px < 2; ++px) {
        const int y = px ? yB : yA;
        const float2 f = px ? fB : fA;
        const size_t oi = px ? iB : iA;

        const float qy = (float)y - f.x;
        const float qx = (float)x - f.y;
        float fy = floorf(qy);
        fy = fminf(fmaxf(fy, 0.0f), (float)(BW_H - 2));
        float fx = floorf(qx);
        fx = fminf(fmaxf(fx, 0.0f), (float)(BW_W - 2));
        const float ay = fminf(fmaxf(qy - fy, 0.0f), 1.0f);
        const float ax = fminf(fmaxf(qx - fx, 0.0f), 1.0f);
        const int iy = (int)fy;
        const int ix = (int)fx;

        float* __restrict__ o = out + oi * BW_C;

        const int lr = iy - ry0;  // LDS row of top-left neighbor
        const int lc = ix - rx0;
        if ((unsigned)lr < (unsigned)(S_ROWS - 1) &&
            (unsigned)lc < (unsigned)(S_COLS - 1)) {
            // fast path: aligned b128 LDS gathers
            const float4 tl = tile[lr * S_COLS + lc];
            const float4 tr = tile[lr * S_COLS + lc + 1];
            const float4 bl = tile[(lr + 1) * S_COLS + lc];
            const float4 br = tile[(lr + 1) * S_COLS + lc + 1];
            lerp_store(tl.x, tl.y, tl.z, tr.x, tr.y, tr.z,
                       bl.x, bl.y, bl.z, br.x, br.y, br.z, ax, ay, o);
        } else {
            // rare fallback: direct global gather (P ~ 5.7e-7 per pixel)
            const float* __restrict__ p0 = imgb + ((size_t)iy * BW_W + ix) * BW_C;
            const float* __restrict__ p1 = p0 + BW_W * BW_C;
            lerp_store(p0[0], p0[1], p0[2], p0[3], p0[4], p0[5],
                       p1[0], p1[1], p1[2], p1[3], p1[4], p1[5], ax, ay, o);
        }
    }
}

extern "C" void kernel_launch(void* const* d_in, const int* in_sizes, int n_in,
                              void* d_out, int out_size, void* d_ws, size_t ws_size,
                              hipStream_t stream) {
    const float* image = (const float*)d_in[0];
    const float* flow  = (const float*)d_in[1];
    float* out = (float*)d_out;

    dim3 block(TILE_W, TILE_H / 2, 1);              // 64 x 4 = 256
    dim3 grid(BW_W / TILE_W, BW_H / TILE_H, BW_B);  // 20 x 90 x 16
    backwarp_kernel<<<grid, block, 0, stream>>>(image, flow, out);
}